// Round 7
// baseline (355.073 us; speedup 1.0000x reference)
//
#include <hip/hip_runtime.h>
#include <hip/hip_bf16.h>

// LSTM: I=32, H=64, O=8, B=4096, T=256, fused single kernel.
// Round 13: GATE-SPLIT 8-wave structure -> 2 waves/SIMD with conserved work.
//  - Model from R10/R12: wall = per-SIMD issue (~775cy) + ~580cy stall from
//    in-order single-wave issue bubbles. Batch TLP exhausted (R11), so split
//    the SAME work: wave pair (p, p+4) owns the same 16 cols; lo wave does
//    gates i,f; hi wave does g,o. Each lane owns 2 cells (lo: D rows 0,1;
//    hi: rows 2,3). Per-SIMD totals conserved; stalls now interleave.
//  - Cross-half gate exchange: 1 ds_write_b128 + 1 ds_read_b128 + barrier B
//    per step (lo sends i,f elems 2,3; hi sends g,o elems 0,1).
//  - Cell math identical to R12 (proven): pre-scaled weights (-log2e /
//    -2log2e), exp2-ready MFMA outputs, combined rcp forms.
//  - x machinery carried by both halves (redundant global reads, L2-absorbed).

#define T_LEN 256
#define I_SZ  32
#define H_SZ  64
#define O_SZ  8
#define BR    16
#define HS    72   // h row stride in shorts

typedef __attribute__((ext_vector_type(8))) short short8;
typedef __attribute__((ext_vector_type(4))) float f32x4;
typedef __attribute__((ext_vector_type(2))) float f32x2;

static __device__ __forceinline__ unsigned fbits(float f) {
    union { float f; unsigned u; } v; v.f = f; return v.u;
}
// two floats -> packed bf16x2 (truncation): elem0 = lo, elem1 = hi
static __device__ __forceinline__ unsigned pk2t(float lo, float hi) {
    return __builtin_amdgcn_perm(fbits(hi), fbits(lo), 0x07060302u);
}
static __device__ __forceinline__ short f2bf_rne(float f) {   // init-time only
    union { __hip_bfloat16 b; short s; } u;
    u.b = __float2bfloat16(f);
    return u.s;
}
static __device__ __forceinline__ f32x2 rcp2(f32x2 d) {
    f32x2 r;
    r.x = __builtin_amdgcn_rcpf(d.x);
    r.y = __builtin_amdgcn_rcpf(d.y);
    return r;
}
static __device__ __forceinline__ f32x2 exp2_2(f32x2 m) {
    f32x2 e;
    e.x = __builtin_amdgcn_exp2f(m.x);
    e.y = __builtin_amdgcn_exp2f(m.y);
    return e;
}
static __device__ __forceinline__ f32x2 clamp2(f32x2 x, float lo, float hi) {
    f32x2 r;
    r.x = __builtin_amdgcn_fmed3f(x.x, lo, hi);
    r.y = __builtin_amdgcn_fmed3f(x.y, lo, hi);
    return r;
}
static __device__ __forceinline__ f32x2 fma2(f32x2 a, f32x2 b, f32x2 c) {
    return __builtin_elementwise_fma(a, b, c);
}

#define LOG2E     1.4426950408889634f
#define TWO_LOG2E 2.8853900817779268f
#define ECLAMP    28.8f   // exp2-domain clamp: tanh saturation at |x|=10

__global__ __launch_bounds__(512, 1)
void lstm_fused_kernel(const float* __restrict__ x,
                       const float* __restrict__ W_ih,
                       const float* __restrict__ W_hh,
                       const float* __restrict__ b_ih,
                       const float* __restrict__ b_hh,
                       const float* __restrict__ W_fc,
                       const float* __restrict__ b_fc,
                       float* __restrict__ out)
{
    __shared__ short hbuf[2][BR][HS];   // h double buffer, bf16, 16 real rows
    __shared__ float Hf[BR][64];
    __shared__ f32x4 xch[2][4][64];     // [half][pair][lane] gate exchange

    const int tid   = threadIdx.x;
    const int wave  = tid >> 6;
    const int lane  = tid & 63;
    const int quad  = lane >> 4;
    const int nlow  = lane & 15;
    const int pair  = wave & 3;          // col group
    const int half  = wave >> 2;         // 0: gates i,f ; 1: gates g,o
    const int jw    = pair * 16 + nlow;  // hidden col this pair owns
    const int rbase = quad * 4;
    const int myr   = rbase + half * 2;  // this wave's 2 cell rows
    const int b0    = blockIdx.x * BR;

    // ---- weights for this wave's 2 gates, PRE-SCALED (exp2-ready).
    short8 bfrag[2][3];
    f32x2  biasf2[2];
    f32x4  biasf[2];
    for (int gg = 0; gg < 2; ++gg) {
        const int g = half * 2 + gg;     // global gate index
        const float scale = (g == 2) ? -TWO_LOG2E : -LOG2E;
        const int col = g * 64 + jw;
        {
            const float* wr = W_ih + col * I_SZ + quad * 8;
            short8 f;
            #pragma unroll
            for (int e = 0; e < 8; ++e) f[e] = f2bf_rne(scale * wr[e]);
            bfrag[gg][0] = f;
        }
        #pragma unroll
        for (int kt = 1; kt < 3; ++kt) {
            const float* wr = W_hh + col * H_SZ + (kt - 1) * 32 + quad * 8;
            short8 f;
            #pragma unroll
            for (int e = 0; e < 8; ++e) f[e] = f2bf_rne(scale * wr[e]);
            bfrag[gg][kt] = f;
        }
        const float bg = scale * (b_ih[col] + b_hh[col]);
        biasf[gg] = (f32x4){bg, bg, bg, bg};
        biasf2[gg] = (f32x2){bg, bg};
        (void)biasf2;
    }

    // ---- zero h buffers (h0 = 0)
    for (int q = tid; q < 2 * BR * HS; q += 512) ((short*)hbuf)[q] = (short)0;

    // ---- x machinery: lane owns x[b0+nlow][t][quad*8 .. +7] (A row = nlow).
    const float* xb = x + ((size_t)(b0 + nlow) * T_LEN) * I_SZ + quad * 8;

    float4 nx[16];                        // next-chunk fp32 (8 steps x 8 floats)
    short8 sc[8];                         // current-chunk bf16 fragments
    #pragma unroll
    for (int s = 0; s < 8; ++s) {
        nx[2*s]   = *(const float4*)(xb + s * I_SZ);
        nx[2*s+1] = *(const float4*)(xb + s * I_SZ + 4);
    }
    #pragma unroll
    for (int s = 0; s < 8; ++s) {
        union { uint4 u; short8 v; } w;
        w.u.x = pk2t(nx[2*s].x,   nx[2*s].y);
        w.u.y = pk2t(nx[2*s].z,   nx[2*s].w);
        w.u.z = pk2t(nx[2*s+1].x, nx[2*s+1].y);
        w.u.w = pk2t(nx[2*s+1].z, nx[2*s+1].w);
        sc[s] = w.v;
    }

    // LDS addresses: read A rows by nlow; write own 2 cell rows at col jw.
    const short* rb[2] = { &hbuf[0][nlow][quad * 8], &hbuf[1][nlow][quad * 8] };
    short*       wb[2] = { &hbuf[0][myr][jw],        &hbuf[1][myr][jw] };

    f32x2 cc = {0.f, 0.f};
    f32x2 hh = {0.f, 0.f};

    // ---- x-projection pipeline for this wave's 2 gates.
    f32x4 preacc[2];
    #pragma unroll
    for (int gg = 0; gg < 2; ++gg)
        preacc[gg] = __builtin_amdgcn_mfma_f32_16x16x32_bf16(sc[0], bfrag[gg][0], biasf[gg], 0, 0, 0);

    for (int ch = 0; ch < 32; ++ch) {
        #pragma unroll
        for (int tc = 0; tc < 8; ++tc) {
            const int t = ch * 8 + tc;

            __syncthreads();             // barrier A: h_{t-1} visible

            // h fragments: A[m = nlow][k = 32*kt + quad*8 + e]
            const short* hr = rb[t & 1];
            short8 a1 = *(const short8*)(hr);        // h cols  0..31
            short8 a2 = *(const short8*)(hr + 32);   // h cols 32..63

            // issue next chunk's global loads early in the chunk
            if (tc == 0 && ch + 1 < 32) {
                const float* nxt = xb + (t + 8) * I_SZ;
                #pragma unroll
                for (int s = 0; s < 8; ++s) {
                    nx[2*s]   = *(const float4*)(nxt + s * I_SZ);
                    nx[2*s+1] = *(const float4*)(nxt + s * I_SZ + 4);
                }
            }

            // 2 gate chains, 2 MFMAs deep (C = preacc from x-proj pipeline).
            f32x4 acc[2];
            #pragma unroll
            for (int gg = 0; gg < 2; ++gg) {
                f32x4 a = __builtin_amdgcn_mfma_f32_16x16x32_bf16(a1, bfrag[gg][1], preacc[gg], 0, 0, 0);
                a = __builtin_amdgcn_mfma_f32_16x16x32_bf16(a2, bfrag[gg][2], a, 0, 0, 0);
                acc[gg] = a;
            }

            // exchange write: send the half this wave does NOT consume.
            f32x4 send;
            if (half == 0) send = (f32x4){acc[0].z, acc[0].w, acc[1].z, acc[1].w};
            else           send = (f32x4){acc[0].x, acc[0].y, acc[1].x, acc[1].y};
            xch[half][pair][lane] = send;

            // convert next chunk once its loads landed (7 steps of cover)
            if (tc == 7 && ch + 1 < 32) {
                #pragma unroll
                for (int s = 0; s < 8; ++s) {
                    union { uint4 u; short8 v; } w;
                    w.u.x = pk2t(nx[2*s].x,   nx[2*s].y);
                    w.u.y = pk2t(nx[2*s].z,   nx[2*s].w);
                    w.u.z = pk2t(nx[2*s+1].x, nx[2*s+1].y);
                    w.u.w = pk2t(nx[2*s+1].z, nx[2*s+1].w);
                    sc[s] = w.v;
                }
            }

            // x-projection for step t+1 (independent filler before barrier B)
            const short8 nax = sc[(tc + 1) & 7];
            #pragma unroll
            for (int gg = 0; gg < 2; ++gg)
                preacc[gg] = __builtin_amdgcn_mfma_f32_16x16x32_bf16(nax, bfrag[gg][0], biasf[gg], 0, 0, 0);

            __syncthreads();             // barrier B: exchange visible

            const f32x4 r = xch[half ^ 1][pair][lane];

            // assemble this wave's 2 cells' gate pre-activations (exp2-ready)
            f32x2 pi, pf, pg, po;
            if (half == 0) {
                pi = (f32x2){acc[0].x, acc[0].y};
                pf = (f32x2){acc[1].x, acc[1].y};
                pg = (f32x2){r.x, r.y};
                po = (f32x2){r.z, r.w};
            } else {
                pi = (f32x2){r.x, r.y};
                pf = (f32x2){r.z, r.w};
                pg = (f32x2){acc[0].z, acc[0].w};
                po = (f32x2){acc[1].z, acc[1].w};
            }

            // ---- cell update (R12 math, f32x2): 2 cells/lane.
            f32x2 ei = exp2_2(pi);
            f32x2 ef = exp2_2(pf);
            f32x2 eg = exp2_2(clamp2(pg, -ECLAMP, ECLAMP));
            f32x2 eo = exp2_2(po);
            f32x2 fv = rcp2(ef + 1.0f);                              // sigmoid(f)
            f32x2 ig = (1.0f - eg) * rcp2((ei + 1.0f) * (eg + 1.0f)); // sig(i)*tanh(g)
            cc = fma2(fv, cc, ig);
            f32x2 ec = exp2_2(clamp2(cc * (-TWO_LOG2E), -ECLAMP, ECLAMP));
            hh = (1.0f - ec) * rcp2((eo + 1.0f) * (ec + 1.0f));      // sig(o)*tanh(c)

            // h store: truncation pack, 2x ds_write_b16
            short* hw = wb[(t + 1) & 1];
            hw[0]  = (short)((fbits(hh.x) + 0x8000u) >> 16);
            hw[HS] = (short)((fbits(hh.y) + 0x8000u) >> 16);
        }
    }

    // ---- epilogue: out[b0+r][o] = h_T[r] . W_fc[o] + b_fc[o]  (fp32 h)
    Hf[myr + 0][jw] = hh.x;
    Hf[myr + 1][jw] = hh.y;
    __syncthreads();

    if (tid < BR * O_SZ) {               // 128 threads
        const int r = tid >> 3;
        const int o = tid & 7;
        const float* wf = W_fc + o * H_SZ;
        float acc = b_fc[o];
        #pragma unroll
        for (int jx = 0; jx < H_SZ; ++jx) acc += Hf[r][jx] * wf[jx];
        out[(size_t)(b0 + r) * O_SZ + o] = acc;
    }
}

extern "C" void kernel_launch(void* const* d_in, const int* in_sizes, int n_in,
                              void* d_out, int out_size, void* d_ws, size_t ws_size,
                              hipStream_t stream) {
    const float* x    = (const float*)d_in[0];
    const float* W_ih = (const float*)d_in[1];
    const float* W_hh = (const float*)d_in[2];
    const float* b_ih = (const float*)d_in[3];
    const float* b_hh = (const float*)d_in[4];
    const float* W_fc = (const float*)d_in[5];
    const float* b_fc = (const float*)d_in[6];
    float* out = (float*)d_out;

    const int B = 4096;
    lstm_fused_kernel<<<dim3(B / BR), dim3(512), 0, stream>>>(
        x, W_ih, W_hh, b_ih, b_hh, W_fc, b_fc, out);
}

// Round 9
// 323.962 us; speedup vs baseline: 1.0960x; 1.0960x over previous
//
#include <hip/hip_runtime.h>
#include <hip/hip_bf16.h>

// LSTM: I=32, H=64, O=8, B=4096, T=256, fused single kernel.
// Round 14 (resubmit; prior run was an infra failure "container failed
// twice" — no kernel data): TRANSPOSED-GEMM gate packing -> 2 waves/SIMD,
// ONE barrier, zero exchange, conserved work.
//  - R13 failed because a cell's 4 gates landed in 4 waves (exchange+barrier).
//    Fix: compute D[gatecol][batchrow] (A = weights, B = x/h) and pack the
//    M-tile as m = 4*colgroup + gate. D fragment gives lane (q,n) rows
//    4q..4q+3, col n  =>  acc[0..3] = gates i,f,g,o of cell (hidden col
//    tilebase+q, batch row n). All 4 gates in ONE lane. No exchange.
//  - 8 waves x 2 tiles x 3 MFMA = 48 MFMA/CU-step (= R12, conserved).
//    2 cells/lane, activation totals conserved. ONE __syncthreads per step.
//  - B-fragments (x and h) are bit-identical to R12's proven A-fragments:
//    lane (q,n) holds row n, k = q*8..+7. Same ds_reads, same x machinery.
//  - Cell math = R12/R13 proven: weights pre-scaled -log2e / -2log2e,
//    exp2-ready MFMA outputs, combined-rcp forms, f32x2 over the 2 tiles.

#define T_LEN 256
#define I_SZ  32
#define H_SZ  64
#define O_SZ  8
#define BR    16
#define HS    72   // h row stride in shorts

typedef __attribute__((ext_vector_type(8))) short short8;
typedef __attribute__((ext_vector_type(4))) float f32x4;
typedef __attribute__((ext_vector_type(2))) float f32x2;

static __device__ __forceinline__ unsigned fbits(float f) {
    union { float f; unsigned u; } v; v.f = f; return v.u;
}
// two floats -> packed bf16x2 (truncation): elem0 = lo, elem1 = hi
static __device__ __forceinline__ unsigned pk2t(float lo, float hi) {
    return __builtin_amdgcn_perm(fbits(hi), fbits(lo), 0x07060302u);
}
static __device__ __forceinline__ short f2bf_rne(float f) {   // init-time only
    union { __hip_bfloat16 b; short s; } u;
    u.b = __float2bfloat16(f);
    return u.s;
}
static __device__ __forceinline__ f32x2 rcp2(f32x2 d) {
    f32x2 r;
    r.x = __builtin_amdgcn_rcpf(d.x);
    r.y = __builtin_amdgcn_rcpf(d.y);
    return r;
}
static __device__ __forceinline__ f32x2 exp2_2(f32x2 m) {
    f32x2 e;
    e.x = __builtin_amdgcn_exp2f(m.x);
    e.y = __builtin_amdgcn_exp2f(m.y);
    return e;
}
static __device__ __forceinline__ f32x2 clamp2(f32x2 x, float lo, float hi) {
    f32x2 r;
    r.x = __builtin_amdgcn_fmed3f(x.x, lo, hi);
    r.y = __builtin_amdgcn_fmed3f(x.y, lo, hi);
    return r;
}
static __device__ __forceinline__ f32x2 fma2(f32x2 a, f32x2 b, f32x2 c) {
    return __builtin_elementwise_fma(a, b, c);
}

#define LOG2E     1.4426950408889634f
#define TWO_LOG2E 2.8853900817779268f
#define ECLAMP    28.8f   // exp2-domain clamp: tanh saturation at |x|=10

__global__ __launch_bounds__(512, 1)
void lstm_fused_kernel(const float* __restrict__ x,
                       const float* __restrict__ W_ih,
                       const float* __restrict__ W_hh,
                       const float* __restrict__ b_ih,
                       const float* __restrict__ b_hh,
                       const float* __restrict__ W_fc,
                       const float* __restrict__ b_fc,
                       float* __restrict__ out)
{
    __shared__ short hbuf[2][BR][HS];   // h double buffer, bf16, 16 real rows
    __shared__ float Hf[BR][64];

    const int tid   = threadIdx.x;
    const int wave  = tid >> 6;          // 0..7
    const int lane  = tid & 63;
    const int quad  = lane >> 4;         // q = colgroup within tile
    const int nlow  = lane & 15;         // batch row (B-frag col / D col)
    const int b0    = blockIdx.x * BR;

    // This wave's 2 tiles cover hidden cols [wave*8, wave*8+8).
    const int tb0 = wave * 8;
    const int tb1 = wave * 8 + 4;
    const int hc0 = tb0 + quad;          // cell hidden col, tile 0
    const int hc1 = tb1 + quad;          // cell hidden col, tile 1

    // ---- A fragments = PRE-SCALED weights, packed M-rows m = 4*c + gate.
    // A-fragment layout: lane (q,n) holds A[row = nlow][k = q*8 + e].
    //   row nlow -> gate = nlow&3, colgroup c = nlow>>2, gatecol = gate*64+tb+c
    // kt=0: W_ih (k = I features); kt=1,2: W_hh k 0..31 / 32..63.
    short8 wfrag[2][3];
    f32x4  biasC[2];
    #pragma unroll
    for (int tile = 0; tile < 2; ++tile) {
        const int tb = (tile == 0) ? tb0 : tb1;
        const int gate = nlow & 3;
        const int c    = nlow >> 2;
        const int gc   = gate * 64 + tb + c;
        const float scale = (gate == 2) ? -TWO_LOG2E : -LOG2E;
        {
            const float* wr = W_ih + gc * I_SZ + quad * 8;
            short8 f;
            #pragma unroll
            for (int e = 0; e < 8; ++e) f[e] = f2bf_rne(scale * wr[e]);
            wfrag[tile][0] = f;
        }
        #pragma unroll
        for (int kt = 1; kt < 3; ++kt) {
            const float* wr = W_hh + gc * H_SZ + (kt - 1) * 32 + quad * 8;
            short8 f;
            #pragma unroll
            for (int e = 0; e < 8; ++e) f[e] = f2bf_rne(scale * wr[e]);
            wfrag[tile][kt] = f;
        }
        // C/D layout: lane (q,n) rows 4q+k (k = gate), col n.
        f32x4 bc;
        #pragma unroll
        for (int k = 0; k < 4; ++k) {
            const int gck = k * 64 + tb + quad;
            const float sk = (k == 2) ? -TWO_LOG2E : -LOG2E;
            bc[k] = sk * (b_ih[gck] + b_hh[gck]);
        }
        biasC[tile] = bc;
    }

    // ---- zero h buffers (h0 = 0)
    for (int q = tid; q < 2 * BR * HS; q += 512) ((short*)hbuf)[q] = (short)0;

    // ---- x machinery (identical to R12): lane owns x[b0+nlow][t][quad*8..+7]
    const float* xb = x + ((size_t)(b0 + nlow) * T_LEN) * I_SZ + quad * 8;

    float4 nx[16];                        // next-chunk fp32 (8 steps x 8 floats)
    short8 sc[8];                         // current-chunk bf16 fragments
    #pragma unroll
    for (int s = 0; s < 8; ++s) {
        nx[2*s]   = *(const float4*)(xb + s * I_SZ);
        nx[2*s+1] = *(const float4*)(xb + s * I_SZ + 4);
    }
    #pragma unroll
    for (int s = 0; s < 8; ++s) {
        union { uint4 u; short8 v; } w;
        w.u.x = pk2t(nx[2*s].x,   nx[2*s].y);
        w.u.y = pk2t(nx[2*s].z,   nx[2*s].w);
        w.u.z = pk2t(nx[2*s+1].x, nx[2*s+1].y);
        w.u.w = pk2t(nx[2*s+1].z, nx[2*s+1].w);
        sc[s] = w.v;
    }

    // LDS addresses: read B-frag rows by nlow (same as R12); write 2 cells.
    const short* rb[2] = { &hbuf[0][nlow][quad * 8], &hbuf[1][nlow][quad * 8] };
    short*       wr0   = &hbuf[0][nlow][0];
    short*       wr1   = &hbuf[1][nlow][0];

    f32x2 cc = {0.f, 0.f};   // cells: {tile0 (hc0), tile1 (hc1)}, row nlow
    f32x2 hh = {0.f, 0.f};

    // ---- x-projection pipeline: preacc[tile] = W_ih-tile * x_t + bias.
    f32x4 preacc[2];
    #pragma unroll
    for (int tile = 0; tile < 2; ++tile)
        preacc[tile] = __builtin_amdgcn_mfma_f32_16x16x32_bf16(wfrag[tile][0], sc[0], biasC[tile], 0, 0, 0);

    for (int ch = 0; ch < 32; ++ch) {
        #pragma unroll
        for (int tc = 0; tc < 8; ++tc) {
            const int t = ch * 8 + tc;

            __syncthreads();             // h_{t-1} (and at t=0 the zeroing) visible

            // h B-fragments: lane (q,n) holds h[row n][k = 32*kt + q*8 + e]
            const short* hr = rb[t & 1];
            short8 a1 = *(const short8*)(hr);        // h k  0..31
            short8 a2 = *(const short8*)(hr + 32);   // h k 32..63

            // issue next chunk's global loads early in the chunk
            if (tc == 0 && ch + 1 < 32) {
                const float* nxt = xb + (t + 8) * I_SZ;
                #pragma unroll
                for (int s = 0; s < 8; ++s) {
                    nx[2*s]   = *(const float4*)(nxt + s * I_SZ);
                    nx[2*s+1] = *(const float4*)(nxt + s * I_SZ + 4);
                }
            }

            // 2 tile chains, 2 MFMAs deep (C = preacc from x-proj pipeline).
            f32x4 acc[2];
            #pragma unroll
            for (int tile = 0; tile < 2; ++tile) {
                f32x4 a = __builtin_amdgcn_mfma_f32_16x16x32_bf16(wfrag[tile][1], a1, preacc[tile], 0, 0, 0);
                a = __builtin_amdgcn_mfma_f32_16x16x32_bf16(wfrag[tile][2], a2, a, 0, 0, 0);
                acc[tile] = a;
            }

            // convert next chunk once its loads landed (7 steps of cover)
            if (tc == 7 && ch + 1 < 32) {
                #pragma unroll
                for (int s = 0; s < 8; ++s) {
                    union { uint4 u; short8 v; } w;
                    w.u.x = pk2t(nx[2*s].x,   nx[2*s].y);
                    w.u.y = pk2t(nx[2*s].z,   nx[2*s].w);
                    w.u.z = pk2t(nx[2*s+1].x, nx[2*s+1].y);
                    w.u.w = pk2t(nx[2*s+1].z, nx[2*s+1].w);
                    sc[s] = w.v;
                }
            }

            // x-projection for step t+1 (independent filler).
            const short8 nax = sc[(tc + 1) & 7];
            #pragma unroll
            for (int tile = 0; tile < 2; ++tile)
                preacc[tile] = __builtin_amdgcn_mfma_f32_16x16x32_bf16(wfrag[tile][0], nax, biasC[tile], 0, 0, 0);

            // ---- cell update: 2 cells/lane, all 4 gates local in acc[tile].
            // acc[tile][0..3] = exp2-ready {i,f,g,o} of cell (hc_tile, nlow).
            f32x2 pi = {acc[0][0], acc[1][0]};
            f32x2 pf = {acc[0][1], acc[1][1]};
            f32x2 pg = {acc[0][2], acc[1][2]};
            f32x2 po = {acc[0][3], acc[1][3]};

            f32x2 ei = exp2_2(pi);
            f32x2 ef = exp2_2(pf);
            f32x2 eg = exp2_2(clamp2(pg, -ECLAMP, ECLAMP));
            f32x2 eo = exp2_2(po);
            f32x2 fv = rcp2(ef + 1.0f);                              // sigmoid(f)
            f32x2 ig = (1.0f - eg) * rcp2((ei + 1.0f) * (eg + 1.0f)); // sig(i)*tanh(g)
            cc = fma2(fv, cc, ig);
            f32x2 ec = exp2_2(clamp2(cc * (-TWO_LOG2E), -ECLAMP, ECLAMP));
            hh = (1.0f - ec) * rcp2((eo + 1.0f) * (ec + 1.0f));      // sig(o)*tanh(c)

            // h store: row nlow, cols hc0/hc1. 2x ds_write_b16.
            short* hw = ((t + 1) & 1) ? wr1 : wr0;
            hw[hc0] = (short)((fbits(hh.x) + 0x8000u) >> 16);
            hw[hc1] = (short)((fbits(hh.y) + 0x8000u) >> 16);
        }
    }

    // ---- epilogue: out[b0+r][o] = h_T[r] . W_fc[o] + b_fc[o]  (fp32 h)
    Hf[nlow][hc0] = hh.x;
    Hf[nlow][hc1] = hh.y;
    __syncthreads();

    if (tid < BR * O_SZ) {               // 128 threads
        const int r = tid >> 3;
        const int o = tid & 7;
        const float* wf = W_fc + o * H_SZ;
        float acc = b_fc[o];
        #pragma unroll
        for (int jx = 0; jx < H_SZ; ++jx) acc += Hf[r][jx] * wf[jx];
        out[(size_t)(b0 + r) * O_SZ + o] = acc;
    }
}

extern "C" void kernel_launch(void* const* d_in, const int* in_sizes, int n_in,
                              void* d_out, int out_size, void* d_ws, size_t ws_size,
                              hipStream_t stream) {
    const float* x    = (const float*)d_in[0];
    const float* W_ih = (const float*)d_in[1];
    const float* W_hh = (const float*)d_in[2];
    const float* b_ih = (const float*)d_in[3];
    const float* b_hh = (const float*)d_in[4];
    const float* W_fc = (const float*)d_in[5];
    const float* b_fc = (const float*)d_in[6];
    float* out = (float*)d_out;

    const int B = 4096;
    lstm_fused_kernel<<<dim3(B / BR), dim3(512), 0, stream>>>(
        x, W_ih, W_hh, b_ih, b_hh, W_fc, b_fc, out);
}

// Round 10
// 283.811 us; speedup vs baseline: 1.2511x; 1.1415x over previous
//
#include <hip/hip_runtime.h>
#include <hip/hip_bf16.h>

// LSTM: I=32, H=64, O=8, B=4096, T=256, fused single kernel.
// Round 15: R12 structure (BR=16 full-M, grid 256, 1 blk/CU, 1 wave/SIMD,
// proven 144.7us) + three stall/conflict shaves. TLP is proven exhausted
// (R11/R13/R14 all regressed); this attacks the R12 stall directly.
//  1. Bijective row permutation p(r)=2(r>>2)+8(r&1)+((r>>1)&1) for hbuf:
//     ds_write_b16 banks become 8q+4c+8w+nlow/2 -> all 32 banks, 2-way
//     (free) instead of 4-way. Reads use p(nlow) base (precomputed).
//     Bijection => numerics unchanged.
//  2. preacc double-buffered: the 4 independent x-proj MFMAs issue between
//     the ds_reads and the h-dependent MFMAs -> fill the ~120cy lgkm shadow.
//  3. x-repack de-burst: one fragment conversion per step (tc0 -> current
//     sc[7]; tc1..7 -> next chunk sc[0..6]); branch-free (ch=31 rewrites
//     identical values since nx is not reloaded).
//  - Cell math identical to R12: pre-scaled weights (-log2e / -2log2e),
//    exp2-ready MFMA outputs, combined-rcp activations. Builtins only.

#define T_LEN 256
#define I_SZ  32
#define H_SZ  64
#define O_SZ  8
#define BR    16
#define HS    72   // h row stride in shorts

typedef __attribute__((ext_vector_type(8))) short short8;
typedef __attribute__((ext_vector_type(4))) float f32x4;

static __device__ __forceinline__ unsigned fbits(float f) {
    union { float f; unsigned u; } v; v.f = f; return v.u;
}
// two floats -> packed bf16x2 (truncation): elem0 = lo, elem1 = hi
static __device__ __forceinline__ unsigned pk2t(float lo, float hi) {
    return __builtin_amdgcn_perm(fbits(hi), fbits(lo), 0x07060302u);
}
static __device__ __forceinline__ short f2bf_rne(float f) {   // init-time only
    union { __hip_bfloat16 b; short s; } u;
    u.b = __float2bfloat16(f);
    return u.s;
}
static __device__ __forceinline__ f32x4 rcp4(f32x4 d) {
    f32x4 r;
    r.x = __builtin_amdgcn_rcpf(d.x);
    r.y = __builtin_amdgcn_rcpf(d.y);
    r.z = __builtin_amdgcn_rcpf(d.z);
    r.w = __builtin_amdgcn_rcpf(d.w);
    return r;
}
static __device__ __forceinline__ f32x4 exp2_4(f32x4 m) {
    f32x4 e;
    e.x = __builtin_amdgcn_exp2f(m.x);
    e.y = __builtin_amdgcn_exp2f(m.y);
    e.z = __builtin_amdgcn_exp2f(m.z);
    e.w = __builtin_amdgcn_exp2f(m.w);
    return e;
}
static __device__ __forceinline__ f32x4 clamp4(f32x4 x, float lo, float hi) {
    f32x4 r;
    r.x = __builtin_amdgcn_fmed3f(x.x, lo, hi);
    r.y = __builtin_amdgcn_fmed3f(x.y, lo, hi);
    r.z = __builtin_amdgcn_fmed3f(x.z, lo, hi);
    r.w = __builtin_amdgcn_fmed3f(x.w, lo, hi);
    return r;
}
static __device__ __forceinline__ f32x4 fma4(f32x4 a, f32x4 b, f32x4 c) {
    return __builtin_elementwise_fma(a, b, c);
}

#define LOG2E     1.4426950408889634f
#define TWO_LOG2E 2.8853900817779268f
#define ECLAMP    28.8f   // exp2-domain clamp: tanh saturation at |x|=10

__global__ __launch_bounds__(256, 1)
void lstm_fused_kernel(const float* __restrict__ x,
                       const float* __restrict__ W_ih,
                       const float* __restrict__ W_hh,
                       const float* __restrict__ b_ih,
                       const float* __restrict__ b_hh,
                       const float* __restrict__ W_fc,
                       const float* __restrict__ b_fc,
                       float* __restrict__ out)
{
    __shared__ short hbuf[2][BR][HS];   // h double buffer, bf16, PERMUTED rows
    __shared__ float Hf[BR][64];

    const int tid   = threadIdx.x;
    const int wave  = tid >> 6;
    const int lane  = tid & 63;
    const int quad  = lane >> 4;
    const int nlow  = lane & 15;
    const int jw    = wave * 16 + nlow;  // hidden col this lane's tiles own
    const int rbase = quad * 4;          // logical D rows this lane owns
    const int b0    = blockIdx.x * BR;

    // Bijective row permutation p(r) = 2*(r>>2) + 8*(r&1) + ((r>>1)&1).
    // Spreads the 4 ds_write_b16 across all 32 banks (was 4-way conflict).
    const int prd = 2 * (nlow >> 2) + 8 * (nlow & 1) + ((nlow >> 1) & 1);
    const int pw0 = 2 * quad + 0;    // p(4q+0)
    const int pw1 = 2 * quad + 8;    // p(4q+1)
    const int pw2 = 2 * quad + 1;    // p(4q+2)
    const int pw3 = 2 * quad + 9;    // p(4q+3)

    // ---- B fragments, PRE-SCALED so MFMA emits exp2-ready args.
    // gates 0,1,3 (i,f,o): scale -log2e ; gate 2 (g): scale -2log2e.
    short8 bfrag[4][3];
    f32x4  biasf[4];
    for (int g = 0; g < 4; ++g) {
        const float scale = (g == 2) ? -TWO_LOG2E : -LOG2E;
        const int col = g * 64 + jw;
        {
            const float* wr = W_ih + col * I_SZ + quad * 8;
            short8 f;
            #pragma unroll
            for (int e = 0; e < 8; ++e) f[e] = f2bf_rne(scale * wr[e]);
            bfrag[g][0] = f;
        }
        #pragma unroll
        for (int kt = 1; kt < 3; ++kt) {
            const float* wr = W_hh + col * H_SZ + (kt - 1) * 32 + quad * 8;
            short8 f;
            #pragma unroll
            for (int e = 0; e < 8; ++e) f[e] = f2bf_rne(scale * wr[e]);
            bfrag[g][kt] = f;
        }
        const float bg = scale * (b_ih[col] + b_hh[col]);
        biasf[g] = (f32x4){bg, bg, bg, bg};
    }

    // ---- zero h buffers (h0 = 0; permutation irrelevant for zeros)
    for (int q = tid; q < 2 * BR * HS; q += 256) ((short*)hbuf)[q] = (short)0;

    // ---- x machinery: lane owns x[b0+nlow][t][quad*8 .. +7] (A row = nlow).
    const float* xb = x + ((size_t)(b0 + nlow) * T_LEN) * I_SZ + quad * 8;

    float4 nx[16];                        // in-flight chunk fp32
    short8 sc[8];                         // bf16 fragments
    #pragma unroll
    for (int s = 0; s < 8; ++s) {
        nx[2*s]   = *(const float4*)(xb + s * I_SZ);
        nx[2*s+1] = *(const float4*)(xb + s * I_SZ + 4);
    }
    #pragma unroll
    for (int s = 0; s < 8; ++s) {
        union { uint4 u; short8 v; } w;
        w.u.x = pk2t(nx[2*s].x,   nx[2*s].y);
        w.u.y = pk2t(nx[2*s].z,   nx[2*s].w);
        w.u.z = pk2t(nx[2*s+1].x, nx[2*s+1].y);
        w.u.w = pk2t(nx[2*s+1].z, nx[2*s+1].w);
        sc[s] = w.v;
    }

    // LDS addresses: read A rows via permuted p(nlow); write via pw* offsets.
    const short* rb[2] = { &hbuf[0][prd][quad * 8], &hbuf[1][prd][quad * 8] };
    short*       wb[2] = { &hbuf[0][0][jw],         &hbuf[1][0][jw] };

    f32x4 cc = {0.f, 0.f, 0.f, 0.f};
    f32x4 hh = {0.f, 0.f, 0.f, 0.f};

    // ---- x-projection pipeline: preacc[g] = W_ih·x_t + bias for step t.
    f32x4 preacc[4];
    #pragma unroll
    for (int g = 0; g < 4; ++g)
        preacc[g] = __builtin_amdgcn_mfma_f32_16x16x32_bf16(sc[0], bfrag[g][0], biasf[g], 0, 0, 0);

    for (int ch = 0; ch < 32; ++ch) {
        #pragma unroll
        for (int tc = 0; tc < 8; ++tc) {
            const int t = ch * 8 + tc;

            __syncthreads();             // h_{t-1} (and at t=0 the zeroing) visible

            // h fragments (permuted row base): issue reads immediately.
            const short* hr = rb[t & 1];
            short8 a1 = *(const short8*)(hr);        // h k  0..31
            short8 a2 = *(const short8*)(hr + 32);   // h k 32..63

            if (tc == 0) {
                // finish CURRENT chunk's sc[7] from old nx (before reload)
                union { uint4 u; short8 v; } w;
                w.u.x = pk2t(nx[14].x, nx[14].y);
                w.u.y = pk2t(nx[14].z, nx[14].w);
                w.u.z = pk2t(nx[15].x, nx[15].y);
                w.u.w = pk2t(nx[15].z, nx[15].w);
                sc[7] = w.v;
                if (ch + 1 < 32) {       // issue next chunk's global loads
                    const float* nxt = xb + (t + 8) * I_SZ;
                    #pragma unroll
                    for (int s = 0; s < 8; ++s) {
                        nx[2*s]   = *(const float4*)(nxt + s * I_SZ);
                        nx[2*s+1] = *(const float4*)(nxt + s * I_SZ + 4);
                    }
                }
            }

            // x-proj MFMAs for step t+1: independent of a1/a2 -> these fill
            // the ds_read lgkm shadow before the h-dependent chains below.
            const short8 nax = sc[(tc + 1) & 7];
            f32x4 preacc_n[4];
            #pragma unroll
            for (int g = 0; g < 4; ++g)
                preacc_n[g] = __builtin_amdgcn_mfma_f32_16x16x32_bf16(nax, bfrag[g][0], biasf[g], 0, 0, 0);

            // h-dependent chains on OLD preacc (2 MFMAs deep).
            f32x4 acc[4];
            #pragma unroll
            for (int g = 0; g < 4; ++g) {
                f32x4 a = __builtin_amdgcn_mfma_f32_16x16x32_bf16(a1, bfrag[g][1], preacc[g], 0, 0, 0);
                a = __builtin_amdgcn_mfma_f32_16x16x32_bf16(a2, bfrag[g][2], a, 0, 0, 0);
                acc[g] = a;
            }

            // de-burst repack: one next-chunk fragment per step (tc>=1).
            // Branch-free: at ch=31 nx is stale == same chunk -> rewrites
            // identical values (correct, unused-slot safe).
            if (tc >= 1) {
                const int s = tc - 1;
                union { uint4 u; short8 v; } w;
                w.u.x = pk2t(nx[2*s].x,   nx[2*s].y);
                w.u.y = pk2t(nx[2*s].z,   nx[2*s].w);
                w.u.z = pk2t(nx[2*s+1].x, nx[2*s+1].y);
                w.u.w = pk2t(nx[2*s+1].z, nx[2*s+1].w);
                sc[s] = w.v;
            }

            #pragma unroll
            for (int g = 0; g < 4; ++g) preacc[g] = preacc_n[g];

            // ---- cell update: 4 cells/lane, exp2-ready gate args (R12).
            f32x4 ei = exp2_4(acc[0]);
            f32x4 ef = exp2_4(acc[1]);
            f32x4 eg = exp2_4(clamp4(acc[2], -ECLAMP, ECLAMP));
            f32x4 eo = exp2_4(acc[3]);
            f32x4 fv = rcp4(ef + 1.0f);                               // sigmoid(f)
            f32x4 ig = (1.0f - eg) * rcp4((ei + 1.0f) * (eg + 1.0f)); // sig(i)*tanh(g)
            cc = fma4(fv, cc, ig);
            f32x4 ec = exp2_4(clamp4(cc * (-TWO_LOG2E), -ECLAMP, ECLAMP));
            hh = (1.0f - ec) * rcp4((eo + 1.0f) * (ec + 1.0f));       // sig(o)*tanh(c)

            // h store: truncation pack, 4x ds_write_b16 at PERMUTED rows.
            short* hw = wb[(t + 1) & 1];
            hw[pw0 * HS] = (short)((fbits(hh.x) + 0x8000u) >> 16);
            hw[pw1 * HS] = (short)((fbits(hh.y) + 0x8000u) >> 16);
            hw[pw2 * HS] = (short)((fbits(hh.z) + 0x8000u) >> 16);
            hw[pw3 * HS] = (short)((fbits(hh.w) + 0x8000u) >> 16);
        }
    }

    // ---- epilogue: out[b0+r][o] = h_T[r] . W_fc[o] + b_fc[o]  (fp32 h)
    Hf[rbase + 0][jw] = hh.x;
    Hf[rbase + 1][jw] = hh.y;
    Hf[rbase + 2][jw] = hh.z;
    Hf[rbase + 3][jw] = hh.w;
    __syncthreads();

    if (tid < BR * O_SZ) {               // 128 threads
        const int r = tid >> 3;
        const int o = tid & 7;
        const float* wf = W_fc + o * H_SZ;
        float acc = b_fc[o];
        #pragma unroll
        for (int jx = 0; jx < H_SZ; ++jx) acc += Hf[r][jx] * wf[jx];
        out[(size_t)(b0 + r) * O_SZ + o] = acc;
    }
}

extern "C" void kernel_launch(void* const* d_in, const int* in_sizes, int n_in,
                              void* d_out, int out_size, void* d_ws, size_t ws_size,
                              hipStream_t stream) {
    const float* x    = (const float*)d_in[0];
    const float* W_ih = (const float*)d_in[1];
    const float* W_hh = (const float*)d_in[2];
    const float* b_ih = (const float*)d_in[3];
    const float* b_hh = (const float*)d_in[4];
    const float* W_fc = (const float*)d_in[5];
    const float* b_fc = (const float*)d_in[6];
    float* out = (float*)d_out;

    const int B = 4096;
    lstm_fused_kernel<<<dim3(B / BR), dim3(256), 0, stream>>>(
        x, W_ih, W_hh, b_ih, b_hh, W_fc, b_fc, out);
}

// Round 11
// 281.233 us; speedup vs baseline: 1.2626x; 1.0092x over previous
//
#include <hip/hip_runtime.h>
#include <hip/hip_bf16.h>

// LSTM: I=32, H=64, O=8, B=4096, T=256, fused single kernel.
// Round 16: EXACT R12 structure (144.7us champion: BR=16 full-M, grid 256,
// 1 blk/CU, pre-scaled exp2-ready weights, combined-rcp activations)
// with ONE change: __syncthreads() -> lgkmcnt(0)-only barrier.
//  - __syncthreads emits s_waitcnt vmcnt(0) expcnt(0) lgkmcnt(0) + s_barrier:
//    every one of the 256 per-step barriers force-drains the 16 in-flight
//    x-chunk HBM loads (issued at tc==0, needed ~8 steps later). The barrier
//    only needs LDS ordering (h double buffer), i.e. lgkmcnt(0).
//  - asm volatile("s_waitcnt lgkmcnt(0); s_barrier" ::: "memory"): wave's
//    ds_writes drained before barrier; "memory" clobber pins all LDS ops on
//    the correct side. x-loads stay vmcnt-tracked by the compiler at their
//    actual use (tc==7 repack) - loads now span barriers (T4-style).
//  - No inline-asm ds ops anywhere (rule-#18 hazard class avoided).
//  - R15's three shaves reverted (measured neutral-to-negative; conflicts
//    counter proved identical 2203648 with and without the permutation).

#define T_LEN 256
#define I_SZ  32
#define H_SZ  64
#define O_SZ  8
#define BR    16
#define HS    72   // h row stride in shorts

typedef __attribute__((ext_vector_type(8))) short short8;
typedef __attribute__((ext_vector_type(4))) float f32x4;

static __device__ __forceinline__ unsigned fbits(float f) {
    union { float f; unsigned u; } v; v.f = f; return v.u;
}
// two floats -> packed bf16x2 (truncation): elem0 = lo, elem1 = hi
static __device__ __forceinline__ unsigned pk2t(float lo, float hi) {
    return __builtin_amdgcn_perm(fbits(hi), fbits(lo), 0x07060302u);
}
static __device__ __forceinline__ short f2bf_rne(float f) {   // init-time only
    union { __hip_bfloat16 b; short s; } u;
    u.b = __float2bfloat16(f);
    return u.s;
}
static __device__ __forceinline__ f32x4 rcp4(f32x4 d) {
    f32x4 r;
    r.x = __builtin_amdgcn_rcpf(d.x);
    r.y = __builtin_amdgcn_rcpf(d.y);
    r.z = __builtin_amdgcn_rcpf(d.z);
    r.w = __builtin_amdgcn_rcpf(d.w);
    return r;
}
static __device__ __forceinline__ f32x4 exp2_4(f32x4 m) {
    f32x4 e;
    e.x = __builtin_amdgcn_exp2f(m.x);
    e.y = __builtin_amdgcn_exp2f(m.y);
    e.z = __builtin_amdgcn_exp2f(m.z);
    e.w = __builtin_amdgcn_exp2f(m.w);
    return e;
}
static __device__ __forceinline__ f32x4 clamp4(f32x4 x, float lo, float hi) {
    f32x4 r;
    r.x = __builtin_amdgcn_fmed3f(x.x, lo, hi);
    r.y = __builtin_amdgcn_fmed3f(x.y, lo, hi);
    r.z = __builtin_amdgcn_fmed3f(x.z, lo, hi);
    r.w = __builtin_amdgcn_fmed3f(x.w, lo, hi);
    return r;
}
static __device__ __forceinline__ f32x4 fma4(f32x4 a, f32x4 b, f32x4 c) {
    return __builtin_elementwise_fma(a, b, c);
}
// LDS-only barrier: drain this wave's ds ops, then s_barrier. No vmcnt drain.
static __device__ __forceinline__ void lds_barrier() {
    asm volatile("s_waitcnt lgkmcnt(0)\n\ts_barrier" ::: "memory");
}

#define LOG2E     1.4426950408889634f
#define TWO_LOG2E 2.8853900817779268f
#define ECLAMP    28.8f   // exp2-domain clamp: tanh saturation at |x|=10

__global__ __launch_bounds__(256, 1)
void lstm_fused_kernel(const float* __restrict__ x,
                       const float* __restrict__ W_ih,
                       const float* __restrict__ W_hh,
                       const float* __restrict__ b_ih,
                       const float* __restrict__ b_hh,
                       const float* __restrict__ W_fc,
                       const float* __restrict__ b_fc,
                       float* __restrict__ out)
{
    __shared__ short hbuf[2][BR][HS];   // h double buffer, bf16, 16 real rows
    __shared__ float Hf[BR][64];

    const int tid   = threadIdx.x;
    const int wave  = tid >> 6;
    const int lane  = tid & 63;
    const int quad  = lane >> 4;
    const int nlow  = lane & 15;
    const int jw    = wave * 16 + nlow;  // hidden col this lane's tiles own
    const int rbase = quad * 4;          // D rows this lane owns (real rows)
    const int b0    = blockIdx.x * BR;

    // ---- B fragments, PRE-SCALED so MFMA emits exp2-ready args.
    // gates 0,1,3 (i,f,o): scale -log2e ; gate 2 (g): scale -2log2e.
    short8 bfrag[4][3];
    f32x4  biasf[4];
    for (int g = 0; g < 4; ++g) {
        const float scale = (g == 2) ? -TWO_LOG2E : -LOG2E;
        const int col = g * 64 + jw;
        {
            const float* wr = W_ih + col * I_SZ + quad * 8;
            short8 f;
            #pragma unroll
            for (int e = 0; e < 8; ++e) f[e] = f2bf_rne(scale * wr[e]);
            bfrag[g][0] = f;
        }
        #pragma unroll
        for (int kt = 1; kt < 3; ++kt) {
            const float* wr = W_hh + col * H_SZ + (kt - 1) * 32 + quad * 8;
            short8 f;
            #pragma unroll
            for (int e = 0; e < 8; ++e) f[e] = f2bf_rne(scale * wr[e]);
            bfrag[g][kt] = f;
        }
        const float bg = scale * (b_ih[col] + b_hh[col]);
        biasf[g] = (f32x4){bg, bg, bg, bg};
    }

    // ---- zero h buffers (h0 = 0)
    for (int q = tid; q < 2 * BR * HS; q += 256) ((short*)hbuf)[q] = (short)0;

    // ---- x machinery: lane owns x[b0+nlow][t][quad*8 .. +7] (A row = nlow).
    const float* xb = x + ((size_t)(b0 + nlow) * T_LEN) * I_SZ + quad * 8;

    float4 nx[16];                        // next-chunk fp32 (8 steps x 8 floats)
    short8 sc[8];                         // current-chunk bf16 fragments
    #pragma unroll
    for (int s = 0; s < 8; ++s) {
        nx[2*s]   = *(const float4*)(xb + s * I_SZ);
        nx[2*s+1] = *(const float4*)(xb + s * I_SZ + 4);
    }
    #pragma unroll
    for (int s = 0; s < 8; ++s) {
        union { uint4 u; short8 v; } w;
        w.u.x = pk2t(nx[2*s].x,   nx[2*s].y);
        w.u.y = pk2t(nx[2*s].z,   nx[2*s].w);
        w.u.z = pk2t(nx[2*s+1].x, nx[2*s+1].y);
        w.u.w = pk2t(nx[2*s+1].z, nx[2*s+1].w);
        sc[s] = w.v;
    }

    // LDS addresses: read A rows by nlow; write own 4 cell rows at col jw.
    const short* rb[2] = { &hbuf[0][nlow][quad * 8], &hbuf[1][nlow][quad * 8] };
    short*       wb[2] = { &hbuf[0][rbase][jw],      &hbuf[1][rbase][jw] };

    f32x4 cc = {0.f, 0.f, 0.f, 0.f};
    f32x4 hh = {0.f, 0.f, 0.f, 0.f};

    // ---- x-projection pipeline: preacc[g] = MFMA(ax_t, Wih, bias)
    // for the UPCOMING step, computed one step early (independent filler).
    f32x4 preacc[4];
    #pragma unroll
    for (int g = 0; g < 4; ++g)
        preacc[g] = __builtin_amdgcn_mfma_f32_16x16x32_bf16(sc[0], bfrag[g][0], biasf[g], 0, 0, 0);

    for (int ch = 0; ch < 32; ++ch) {
        #pragma unroll
        for (int tc = 0; tc < 8; ++tc) {
            const int t = ch * 8 + tc;

            lds_barrier();               // h_{t-1} (and at t=0 the zeroing) visible

            // h fragments: A[m = nlow][k = 32*kt + quad*8 + e]
            const short* hr = rb[t & 1];
            short8 a1 = *(const short8*)(hr);        // h cols  0..31
            short8 a2 = *(const short8*)(hr + 32);   // h cols 32..63

            // issue next chunk's global loads early in the chunk
            if (tc == 0 && ch + 1 < 32) {
                const float* nxt = xb + (t + 8) * I_SZ;
                #pragma unroll
                for (int s = 0; s < 8; ++s) {
                    nx[2*s]   = *(const float4*)(nxt + s * I_SZ);
                    nx[2*s+1] = *(const float4*)(nxt + s * I_SZ + 4);
                }
            }

            // post-barrier dependent chain: only 2 MFMAs deep (C = preacc).
            f32x4 acc[4];
            #pragma unroll
            for (int g = 0; g < 4; ++g) {
                f32x4 a = __builtin_amdgcn_mfma_f32_16x16x32_bf16(a1, bfrag[g][1], preacc[g], 0, 0, 0);
                a = __builtin_amdgcn_mfma_f32_16x16x32_bf16(a2, bfrag[g][2], a, 0, 0, 0);
                acc[g] = a;
            }

            // convert next chunk once its loads landed (7 steps of cover);
            // compiler's own vmcnt tracking waits here, not at the barrier.
            if (tc == 7 && ch + 1 < 32) {
                #pragma unroll
                for (int s = 0; s < 8; ++s) {
                    union { uint4 u; short8 v; } w;
                    w.u.x = pk2t(nx[2*s].x,   nx[2*s].y);
                    w.u.y = pk2t(nx[2*s].z,   nx[2*s].w);
                    w.u.z = pk2t(nx[2*s+1].x, nx[2*s+1].y);
                    w.u.w = pk2t(nx[2*s+1].z, nx[2*s+1].w);
                    sc[s] = w.v;
                }
            }

            // x-projection for step t+1: independent of h -> pure filler
            // under the activation trans chains. (Last step: harmless junk.)
            const short8 nax = sc[(tc + 1) & 7];
            #pragma unroll
            for (int g = 0; g < 4; ++g)
                preacc[g] = __builtin_amdgcn_mfma_f32_16x16x32_bf16(nax, bfrag[g][0], biasf[g], 0, 0, 0);

            // ---- cell update: 4 cells/lane, exp2-ready gate args.
            // acc[0]=-log2e*i, acc[1]=-log2e*f, acc[2]=-2log2e*g, acc[3]=-log2e*o
            f32x4 ei = exp2_4(acc[0]);
            f32x4 ef = exp2_4(acc[1]);
            f32x4 eg = exp2_4(clamp4(acc[2], -ECLAMP, ECLAMP));
            f32x4 eo = exp2_4(acc[3]);
            f32x4 fv = rcp4(ef + 1.0f);                            // sigmoid(f)
            f32x4 ig = (1.0f - eg) * rcp4((ei + 1.0f) * (eg + 1.0f)); // sig(i)*tanh(g)
            cc = fma4(fv, cc, ig);
            f32x4 ec = exp2_4(clamp4(cc * (-TWO_LOG2E), -ECLAMP, ECLAMP));
            hh = (1.0f - ec) * rcp4((eo + 1.0f) * (ec + 1.0f));    // sig(o)*tanh(c)

            // h store: truncation pack, 4x ds_write_b16
            short* hw = wb[(t + 1) & 1];
            hw[0 * HS] = (short)((fbits(hh.x) + 0x8000u) >> 16);
            hw[1 * HS] = (short)((fbits(hh.y) + 0x8000u) >> 16);
            hw[2 * HS] = (short)((fbits(hh.z) + 0x8000u) >> 16);
            hw[3 * HS] = (short)((fbits(hh.w) + 0x8000u) >> 16);
        }
    }

    // ---- epilogue: out[b0+r][o] = h_T[r] . W_fc[o] + b_fc[o]  (fp32 h)
    Hf[rbase + 0][jw] = hh.x;
    Hf[rbase + 1][jw] = hh.y;
    Hf[rbase + 2][jw] = hh.z;
    Hf[rbase + 3][jw] = hh.w;
    __syncthreads();

    if (tid < BR * O_SZ) {               // 128 threads
        const int r = tid >> 3;
        const int o = tid & 7;
        const float* wf = W_fc + o * H_SZ;
        float acc = b_fc[o];
        #pragma unroll
        for (int jx = 0; jx < H_SZ; ++jx) acc += Hf[r][jx] * wf[jx];
        out[(size_t)(b0 + r) * O_SZ + o] = acc;
    }
}

extern "C" void kernel_launch(void* const* d_in, const int* in_sizes, int n_in,
                              void* d_out, int out_size, void* d_ws, size_t ws_size,
                              hipStream_t stream) {
    const float* x    = (const float*)d_in[0];
    const float* W_ih = (const float*)d_in[1];
    const float* W_hh = (const float*)d_in[2];
    const float* b_ih = (const float*)d_in[3];
    const float* b_hh = (const float*)d_in[4];
    const float* W_fc = (const float*)d_in[5];
    const float* b_fc = (const float*)d_in[6];
    float* out = (float*)d_out;

    const int B = 4096;
    lstm_fused_kernel<<<dim3(B / BR), dim3(256), 0, stream>>>(
        x, W_ih, W_hh, b_ih, b_hh, W_fc, b_fc, out);
}